// Round 1
// 223.592 us; speedup vs baseline: 1.0316x; 1.0316x over previous
//
#include <hip/hip_runtime.h>
#include <cstdint>
#include <cstddef>

// ---------------------------------------------------------------------------
// MultiHeadAttention forward, MI355X/gfx950.
// cvt(fp32->bf16) -> fused QKV GEMM (MFMA) -> flash attention -> out-proj.
// MFMA layouts (m89/m91/m120):
//   K=32 A-frag: lane l holds A[m=l&15][k=(l>>4)*8+j], j=0..7
//   K=32 B-frag: lane l holds Bt[n=l&15][k=(l>>4)*8+j]
//   K=16 A/B-frag: lane l holds X[.=l&15][k=(l>>4)*4+c], c=0..3
//   C/D: lane l, reg r holds D[m=(l>>4)*4+r][n=l&15]
// R8: attn reshaped to 4 waves x 32 q-rows (2 groups of 16) per block.
// Rationale (R7 counters): MfmaUtil 31 / VALUBusy 48 / HBM 15% and
// SQ_LDS_BANK_CONFLICT 8.5M -> LDS-read issue bound. Each wave read the FULL
// K+V tile (32KB) per key-tile for only 16 q-rows; per-CU LDS-read cycles
// (~98k) + conflicts (~33k) account for ~131k of 161k total cycles.
// Sharing each K-frag/V-frag read across TWO Q/P fragments halves per-q LDS
// traffic (and its address VALU) at unchanged MFMA/softmax work per q.
//  * block 256 thr (4 waves), wave w owns q-rows qt0+w*32..+31; grid (16,32),
//    2 blocks/CU (LDS 64KB), __launch_bounds__(256,2) -> 256-VGPR budget.
//  * K-read base addresses fully lane-constant; per-tile K reads use pure
//    immediate offsets (zero per-tile address VALU for K).
//  * defer-max (T13, THR=8 in exp2 domain): skip the O-rescale pass when no
//    lane's tile-max grew by >8; P bounded by 2^8, fp32 accum absorbs it.
// Kept from R7: XOR-swizzled unpadded K/V LDS (global_load_lds-compatible),
// async-DMA double-buffered staging with ONE barrier per tile, exp2-domain
// softmax (QSCALE folded into Q projection), oproj 64x64 tiles.
// ---------------------------------------------------------------------------

#define D_MODEL 1024
#define NHEAD   16
#define HDIM    64
#define BATCH   2
#define SEQ     2048
#define BT      (BATCH * SEQ)   // 4096

// (1/sqrt(HDIM)) * log2(e) -- folds softmax scale + exp->exp2 conversion
#define QSCALE 0.18033688011112043f

typedef __bf16 bf16;
typedef __bf16 bf16x8 __attribute__((ext_vector_type(8)));
typedef __bf16 bf16x4 __attribute__((ext_vector_type(4)));
typedef float  floatx4 __attribute__((ext_vector_type(4)));
typedef short  short4v __attribute__((ext_vector_type(4)));

#define MFMA16(a, b, c) __builtin_amdgcn_mfma_f32_16x16x32_bf16((a), (b), (c), 0, 0, 0)

__device__ __forceinline__ floatx4 MFMA16B(bf16x4 a, bf16x4 b, floatx4 c) {
  return __builtin_amdgcn_mfma_f32_16x16x16bf16_1k(
      __builtin_bit_cast(short4v, a), __builtin_bit_cast(short4v, b), c, 0, 0, 0);
}

__device__ __forceinline__ float fexp2(float x) {
  return __builtin_amdgcn_exp2f(x);   // v_exp_f32: D = 2^S0
}

// async global->LDS, 16B per lane. LDS dest = wave-uniform base + lane*16.
__device__ __forceinline__ void async_cp16(const bf16* g, bf16* l) {
  __builtin_amdgcn_global_load_lds(
      (__attribute__((address_space(1))) void*)(g),
      (__attribute__((address_space(3))) void*)(l), 16, 0, 0);
}

// ---------------------------------------------------------------------------
// fp32 -> bf16 conversion for q,k,v and the 4 weight matrices.
// ---------------------------------------------------------------------------
__global__ __launch_bounds__(256) void cvt7(
    const float* __restrict__ s0, const float* __restrict__ s1,
    const float* __restrict__ s2, const float* __restrict__ s3,
    const float* __restrict__ s4, const float* __restrict__ s5,
    const float* __restrict__ s6,
    bf16* __restrict__ d0, bf16* __restrict__ d1, bf16* __restrict__ d2,
    bf16* __restrict__ d3, bf16* __restrict__ d4, bf16* __restrict__ d5,
    bf16* __restrict__ d6)
{
  const float* src; bf16* dst; int n4;
  switch (blockIdx.y) {
    case 0:  src = s0; dst = d0; n4 = (BT * D_MODEL) / 4; break;
    case 1:  src = s1; dst = d1; n4 = (BT * D_MODEL) / 4; break;
    case 2:  src = s2; dst = d2; n4 = (BT * D_MODEL) / 4; break;
    case 3:  src = s3; dst = d3; n4 = (D_MODEL * D_MODEL) / 4; break;
    case 4:  src = s4; dst = d4; n4 = (D_MODEL * D_MODEL) / 4; break;
    case 5:  src = s5; dst = d5; n4 = (D_MODEL * D_MODEL) / 4; break;
    default: src = s6; dst = d6; n4 = (D_MODEL * D_MODEL) / 4; break;
  }
  int stride = gridDim.x * blockDim.x;
  for (int i = blockIdx.x * blockDim.x + threadIdx.x; i < n4; i += stride) {
    float4 f = ((const float4*)src)[i];
    bf16x4 h;
    h[0] = (bf16)f.x; h[1] = (bf16)f.y; h[2] = (bf16)f.z; h[3] = (bf16)f.w;
    ((bf16x4*)dst)[i] = h;
  }
}

// ---------------------------------------------------------------------------
// 128x128-tile GEMM core, K=1024, BK=32 (m97 structure).
// ---------------------------------------------------------------------------
__device__ __forceinline__ void gemm128_core(
    const bf16* __restrict__ A, const bf16* __restrict__ W,
    int m0, int n0, bf16* As, bf16* Bs, floatx4 acc[4][4])
{
  const int t = threadIdx.x;
  const int l = t & 63, w = t >> 6;
  const int quad = l >> 4, lr = l & 15;
  const int wm = (w >> 1) * 64, wn = (w & 1) * 64;

  floatx4 z = {0.f, 0.f, 0.f, 0.f};
#pragma unroll
  for (int i = 0; i < 4; i++)
#pragma unroll
    for (int j = 0; j < 4; j++) acc[i][j] = z;

  for (int kt = 0; kt < 1024; kt += 32) {
    __syncthreads();
#pragma unroll
    for (int i = 0; i < 2; i++) {
      int c = i * 256 + t;
      int row = c >> 2, ci = c & 3;
      async_cp16(A + (size_t)(m0 + row) * 1024 + kt + ci * 8,
                 As + (i * 256 + w * 64) * 8);
      async_cp16(W + (size_t)(n0 + row) * 1024 + kt + ci * 8,
                 Bs + (i * 256 + w * 64) * 8);
    }
    __syncthreads();

    bf16x8 af[4], bfr[4];
#pragma unroll
    for (int i = 0; i < 4; i++) {
      af[i]  = *(const bf16x8*)(As + (wm + i * 16 + lr) * 32 + quad * 8);
      bfr[i] = *(const bf16x8*)(Bs + (wn + i * 16 + lr) * 32 + quad * 8);
    }
#pragma unroll
    for (int i = 0; i < 4; i++)
#pragma unroll
      for (int j = 0; j < 4; j++)
        acc[i][j] = MFMA16(af[i], bfr[j], acc[i][j]);
  }
}

// ---------------------------------------------------------------------------
// Fused QKV projection. zid selects (q,Wq)->qh, (k,Wk)->kh, (v,Wv)->vt.
// qh,kh: [B*H][T][64]; v stored TRANSPOSED [B*H][64][T].
// qh is pre-scaled by QSCALE (softmax scale folded + exp2 domain).
// ---------------------------------------------------------------------------
__global__ __launch_bounds__(256) void qkv_gemm(
    const bf16* __restrict__ qb, const bf16* __restrict__ kb, const bf16* __restrict__ vb,
    const bf16* __restrict__ wq, const bf16* __restrict__ wk, const bf16* __restrict__ wv,
    const float* __restrict__ biasq, const float* __restrict__ biask, const float* __restrict__ biasv,
    bf16* __restrict__ qh, bf16* __restrict__ kh, bf16* __restrict__ vt)
{
  __shared__ bf16 As[128 * 32];
  __shared__ bf16 Bs[128 * 32];
  const int zid = blockIdx.z;
  const bf16* A = (zid == 0) ? qb : ((zid == 1) ? kb : vb);
  const bf16* W = (zid == 0) ? wq : ((zid == 1) ? wk : wv);
  const float* bias = (zid == 0) ? biasq : ((zid == 1) ? biask : biasv);
  const int m0 = blockIdx.x * 128, n0 = blockIdx.y * 128;

  floatx4 acc[4][4];
  gemm128_core(A, W, m0, n0, As, Bs, acc);

  const int t = threadIdx.x, l = t & 63, w = t >> 6;
  const int quad = l >> 4, lr = l & 15;
  const int wm = (w >> 1) * 64, wn = (w & 1) * 64;
  const float sc = (zid == 0) ? QSCALE : 1.0f;

  if (zid < 2) {
    bf16* out = (zid == 0) ? qh : kh;
#pragma unroll
    for (int i = 0; i < 4; i++) {
      int mbase = m0 + wm + i * 16 + quad * 4;       // global row (b*2048+t)
      int b  = mbase >> 11;
      int tq = mbase & 2047;
#pragma unroll
      for (int j = 0; j < 4; j++) {
        int n = n0 + wn + j * 16 + lr;               // e = h*64 + dh
        float bv = bias[n];
        int h = n >> 6, dh = n & 63;
        bf16* p = out + ((size_t)((b * NHEAD + h) * SEQ + tq)) * HDIM + dh;
#pragma unroll
        for (int r = 0; r < 4; r++)
          p[(size_t)r * HDIM] = (bf16)((acc[i][j][r] + bv) * sc);
      }
    }
  } else {
#pragma unroll
    for (int i = 0; i < 4; i++) {
      int mbase = m0 + wm + i * 16 + quad * 4;
      int b  = mbase >> 11;
      int tq = mbase & 2047;
#pragma unroll
      for (int j = 0; j < 4; j++) {
        int n = n0 + wn + j * 16 + lr;
        float bv = bias[n];
        int h = n >> 6, dh = n & 63;
        bf16x4 pk;
#pragma unroll
        for (int r = 0; r < 4; r++) pk[r] = (bf16)(acc[i][j][r] + bv);
        *(bf16x4*)(vt + ((size_t)((b * NHEAD + h) * HDIM + dh)) * SEQ + tq) = pk;
      }
    }
  }
}

// ---------------------------------------------------------------------------
// Flash attention. Grid (T/128, B*H), block 256 = 4 waves; wave w owns
// q-rows qt0 + w*32 + {0..31} as TWO groups of 16 (g=0,1; q = g*16 + lr),
// all 128 keys of each tile. Every K-frag / V-frag LDS read feeds BOTH
// groups' MFMAs -> per-q LDS traffic halved vs 16-q waves.
// LDS (double-buffered, 2 x 32 KB):
//   K  [128 rows][64 el],  8-el chunk ci stored at physical ci ^ (row & 7)
//   V^T[ 64 rows][128 el], 8-el chunk ci stored at physical ci ^ (row & 15)
// Staged via global_load_lds: 4 waves x (4 K-seg + 4 V-seg) x 1 KB per tile;
// one barrier per tile (issue DMA for tile k+1 right after barrier k).
// Compute: S^T = MFMA16x16x32(K,Q) (lane q = lr) per group, per-lane exp2
// softmax with defer-max rescale skip, in-register PV via MFMA16x16x16.
// Epilogue: normalize, LDS transpose ([128][72] overlay in buf0), coalesced
// store.
// ---------------------------------------------------------------------------
__global__ __launch_bounds__(256, 2) void attn_fused(
    const bf16* __restrict__ qh, const bf16* __restrict__ kh,
    const bf16* __restrict__ vt, bf16* __restrict__ attn)
{
  __shared__ __align__(16) char smem[65536];   // 2 x (K 16KB + V 16KB)

  const int t = threadIdx.x, l = t & 63, w = t >> 6;   // w in 0..3
  const int quad = l >> 4, lr = l & 15;
  const int bh = blockIdx.y;
  const int qt0 = blockIdx.x * 128;
  const bf16* qg = qh + (size_t)bh * SEQ * HDIM;
  const bf16* kg = kh + (size_t)bh * SEQ * HDIM;
  const bf16* vg = vt + (size_t)bh * HDIM * SEQ;

  // Staging geometry (per wave, per tile): 4 K-segments + 4 V-segments,
  // segment index s = w*4 + i.
  // K seg s: rows s*8+(l>>3), phys chunk l&7  <- global chunk (l&7)^(row&7).
  // V seg s: rows s*4+(l>>4), phys chunk l&15 <- global chunk (l&15)^(row&15).
  const bf16* kseg[4];
  const bf16* vseg[4];
#pragma unroll
  for (int i = 0; i < 4; i++) {
    int s = w * 4 + i;
    int krow = s * 8 + (l >> 3);
    kseg[i] = kg + (size_t)krow * HDIM + (((l & 7) ^ (l >> 3)) * 8);
    int vrow = s * 4 + (l >> 4);
    vseg[i] = vg + (size_t)vrow * SEQ + (((l & 15) ^ (vrow & 15)) * 8);
  }

  // Q B-frags (K=32) for the wave's 32 q-rows: q = qt0 + w*32 + g*16 + lr.
  bf16x8 qf[2][2];
#pragma unroll
  for (int g = 0; g < 2; g++)
#pragma unroll
    for (int ko = 0; ko < 2; ko++)
      qf[g][ko] = *(const bf16x8*)(qg + (size_t)(qt0 + w * 32 + g * 16 + lr) * HDIM
                                   + ko * 32 + quad * 8);

  const floatx4 zz = {0.f, 0.f, 0.f, 0.f};
  floatx4 Oacc[2][4];   // [g] O^T[d = dt*16 + quad*4 + r][q = lr]
#pragma unroll
  for (int g = 0; g < 2; g++)
#pragma unroll
    for (int dt = 0; dt < 4; dt++) Oacc[g][dt] = zz;
  float mrow[2] = {-3.0e38f, -3.0e38f};
  float lrow[2] = {0.f, 0.f};

  auto stage = [&](int buf, int kt) {
    bf16* Kb = (bf16*)(smem + buf * 32768);
    bf16* Vb = (bf16*)(smem + buf * 32768 + 16384);
    int off = kt * 128;
#pragma unroll
    for (int i = 0; i < 4; i++) {
      async_cp16(kseg[i] + (size_t)off * HDIM, Kb + (w * 4 + i) * 512);
      async_cp16(vseg[i] + off,                Vb + (w * 4 + i) * 512);
    }
  };

  // prologue: stage tile 0 into buffer 0
  stage(0, 0);

  for (int kt = 0; kt < 16; kt++) {
    const int p = kt & 1;
    __syncthreads();   // drains vmcnt -> tile kt resident in buf p;
                       // all waves done reading buf 1-p (tile kt-1)
    if (kt + 1 < 16) stage(1 - p, kt + 1);
    const bf16* Ks  = (const bf16*)(smem + p * 32768);
    const bf16* Vts = (const bf16*)(smem + p * 32768 + 16384);

    // K A-frag bases are lane-constant; per-ni reads use immediate offsets.
    const bf16* krow0 = Ks + lr * 64 + ((quad ^ (lr & 7)) * 8);
    const bf16* krow1 = Ks + lr * 64 + (((quad + 4) ^ (lr & 7)) * 8);

    // S^T per group: lane holds S[q=lr][key = ni*16 + quad*4 + r], ni=0..7.
    // Each K-frag pair (k0,k1) is read ONCE and feeds both groups.
    floatx4 s0[8], s1[8];
#pragma unroll
    for (int ni = 0; ni < 8; ni++) {
      bf16x8 k0 = *(const bf16x8*)(krow0 + ni * 1024);
      bf16x8 k1 = *(const bf16x8*)(krow1 + ni * 1024);
      floatx4 a0 = MFMA16(k0, qf[0][0], zz);
      a0 = MFMA16(k1, qf[0][1], a0);
      floatx4 a1 = MFMA16(k0, qf[1][0], zz);
      a1 = MFMA16(k1, qf[1][1], a1);
      s0[ni] = a0;
      s1[ni] = a1;
    }

    // Per-lane online softmax per group (q = lr; exp2 domain, scale
    // pre-folded). defer-max: skip the O/l rescale when no lane's max grew
    // by more than 8 (P then bounded by 2^8 -- fp32 accum absorbs it).
    bf16x4 pk0[8], pk1[8];
#pragma unroll
    for (int g = 0; g < 2; g++) {
      floatx4* sg = g ? s1 : s0;
      bf16x4* pkg = g ? pk1 : pk0;
      float rmax = sg[0][0];
#pragma unroll
      for (int ni = 0; ni < 8; ni++)
#pragma unroll
        for (int r = 0; r < 4; r++) rmax = fmaxf(rmax, sg[ni][r]);
      rmax = fmaxf(rmax, __shfl_xor(rmax, 16, 64));
      rmax = fmaxf(rmax, __shfl_xor(rmax, 32, 64));
      if (!__all(rmax - mrow[g] <= 8.0f)) {
        float mnew = fmaxf(mrow[g], rmax);
        float al = fexp2(mrow[g] - mnew);
        mrow[g] = mnew;
        lrow[g] *= al;
#pragma unroll
        for (int dt = 0; dt < 4; dt++)
#pragma unroll
          for (int r = 0; r < 4; r++) Oacc[g][dt][r] *= al;
      }
      float m = mrow[g];
      float rsum = 0.f;
#pragma unroll
      for (int ni = 0; ni < 8; ni++)
#pragma unroll
        for (int r = 0; r < 4; r++) {
          float pv = fexp2(sg[ni][r] - m);
          rsum += pv;
          pkg[ni][r] = (bf16)pv;
        }
      rsum += __shfl_xor(rsum, 16, 64);
      rsum += __shfl_xor(rsum, 32, 64);
      lrow[g] += rsum;
    }

    // PV: O^T += MFMA_16x16x16(Vt_frag, P_frag); each V-frag read feeds
    // both groups. V logical key-offset ni*16+quad*4 -> chunk
    // c=ni*2+(quad>>1), sub=(quad&1)*4; physical chunk = c ^ lr
    // (V row = dt*16+lr, row&15 == lr).
    const bf16* vbase = Vts + lr * 128 + (quad & 1) * 4;
#pragma unroll
    for (int ni = 0; ni < 8; ni++) {
      const bf16* vp = vbase + (((ni * 2 + (quad >> 1)) ^ lr) * 8);
#pragma unroll
      for (int dt = 0; dt < 4; dt++) {
        bf16x4 vf = *(const bf16x4*)(vp + dt * 2048);
        Oacc[0][dt] = MFMA16B(vf, pk0[ni], Oacc[0][dt]);
        Oacc[1][dt] = MFMA16B(vf, pk1[ni], Oacc[1][dt]);
      }
    }
  }

  // ---- Epilogue: normalize, transpose via LDS, coalesced store. ----
  // Buffer 0 was last read at tile 14; all waves are past the tile-15
  // barrier, so it is free for the Ost overlay ([128][72] padded, 18KB).
  bf16* Ost = (bf16*)smem;
#pragma unroll
  for (int g = 0; g < 2; g++) {
    float inv = 1.0f / lrow[g];
#pragma unroll
    for (int dt = 0; dt < 4; dt++) {
      bf16x4 ov;
#pragma unroll
      for (int r = 0; r < 4; r++) ov[r] = (bf16)(Oacc[g][dt][r] * inv);
      *(bf16x4*)(Ost + (size_t)(w * 32 + g * 16 + lr) * 72 + dt * 16 + quad * 4) = ov;
    }
  }
  __syncthreads();

  // stream Ost [128 q][64 d] to attn[b][qt0+row][h*64 + d], coalesced 16B.
  const int b = bh >> 4, h = bh & 15;
#pragma unroll
  for (int i = 0; i < 4; i++) {
    int c = t + 256 * i;
    int row = c >> 3, ci = c & 7;
    *(int4*)(attn + ((size_t)b * SEQ + qt0 + row) * D_MODEL + h * HDIM + ci * 8) =
        *(const int4*)(Ost + row * 72 + ci * 8);
  }
}

// ---------------------------------------------------------------------------
// Output projection: out = attn @ Wo^T + bo, fp32 output.
// 64x64 tiles -> grid 1024 blocks (4 blocks/CU).
// ---------------------------------------------------------------------------
__global__ __launch_bounds__(256) void oproj_gemm(
    const bf16* __restrict__ attn, const bf16* __restrict__ wo,
    const float* __restrict__ bo, float* __restrict__ out)
{
  __shared__ bf16 As[64 * 32];
  __shared__ bf16 Bs[64 * 32];
  const int m0 = blockIdx.x * 64, n0 = blockIdx.y * 64;
  const int t = threadIdx.x, l = t & 63, w = t >> 6;
  const int quad = l >> 4, lr = l & 15;
  const int wm = (w >> 1) * 32, wn = (w & 1) * 32;

  floatx4 z = {0.f, 0.f, 0.f, 0.f};
  floatx4 acc[2][2];
#pragma unroll
  for (int i = 0; i < 2; i++)
#pragma unroll
    for (int j = 0; j < 2; j++) acc[i][j] = z;

  for (int kt = 0; kt < 1024; kt += 32) {
    __syncthreads();
    {
      int row = t >> 2, ci = t & 3;   // 256 chunks each for A and B
      async_cp16(attn + (size_t)(m0 + row) * 1024 + kt + ci * 8,
                 As + (w * 64) * 8);
      async_cp16(wo + (size_t)(n0 + row) * 1024 + kt + ci * 8,
                 Bs + (w * 64) * 8);
    }
    __syncthreads();

    bf16x8 af[2], bfr[2];
#pragma unroll
    for (int i = 0; i < 2; i++) {
      af[i]  = *(const bf16x8*)(As + (wm + i * 16 + lr) * 32 + quad * 8);
      bfr[i] = *(const bf16x8*)(Bs + (wn + i * 16 + lr) * 32 + quad * 8);
    }
#pragma unroll
    for (int i = 0; i < 2; i++)
#pragma unroll
      for (int j = 0; j < 2; j++)
        acc[i][j] = MFMA16(af[i], bfr[j], acc[i][j]);
  }

#pragma unroll
  for (int i = 0; i < 2; i++) {
    int m = m0 + wm + i * 16 + quad * 4;
#pragma unroll
    for (int j = 0; j < 2; j++) {
      int n = n0 + wn + j * 16 + lr;
      float bv = bo[n];
      float* p = out + (size_t)m * D_MODEL + n;
#pragma unroll
      for (int r = 0; r < 4; r++)
        p[(size_t)r * D_MODEL] = acc[i][j][r] + bv;
    }
  }
}

// ---------------------------------------------------------------------------
extern "C" void kernel_launch(void* const* d_in, const int* in_sizes, int n_in,
                              void* d_out, int out_size, void* d_ws, size_t ws_size,
                              hipStream_t stream)
{
  const float* q  = (const float*)d_in[0];
  const float* k  = (const float*)d_in[1];
  const float* v  = (const float*)d_in[2];
  const float* Wq = (const float*)d_in[3];
  const float* bq = (const float*)d_in[4];
  const float* Wk = (const float*)d_in[5];
  const float* bk = (const float*)d_in[6];
  const float* Wv = (const float*)d_in[7];
  const float* bv = (const float*)d_in[8];
  const float* Wo = (const float*)d_in[9];
  const float* bo = (const float*)d_in[10];

  const size_t NQ = (size_t)BT * D_MODEL;        // 4194304
  const size_t NW = (size_t)D_MODEL * D_MODEL;   // 1048576

  bf16* p = (bf16*)d_ws;
  bf16* qb   = p; p += NQ;
  bf16* kb   = p; p += NQ;
  bf16* vb   = p; p += NQ;
  bf16* wqb  = p; p += NW;
  bf16* wkb  = p; p += NW;
  bf16* wvb  = p; p += NW;
  bf16* wob  = p; p += NW;
  bf16* qhp  = p; p += NQ;   // [B*H][T][64], pre-scaled by QSCALE
  bf16* khp  = p; p += NQ;   // [B*H][T][64]
  bf16* vtp  = p; p += NQ;   // [B*H][64][T]
  bf16* attn = p; p += NQ;   // [B][T][1024]

  cvt7<<<dim3(1024, 7, 1), 256, 0, stream>>>(q, k, v, Wq, Wk, Wv, Wo,
                                             qb, kb, vb, wqb, wkb, wvb, wob);
  qkv_gemm<<<dim3(32, 8, 3), 256, 0, stream>>>(qb, kb, vb, wqb, wkb, wvb,
                                               bq, bk, bv, qhp, khp, vtp);
  attn_fused<<<dim3(16, 32, 1), 256, 0, stream>>>(qhp, khp, vtp, attn);
  oproj_gemm<<<dim3(64, 16, 1), 256, 0, stream>>>(attn, wob, bo, (float*)d_out);
}